// Round 1
// baseline (847.934 us; speedup 1.0000x reference)
//
#include <hip/hip_runtime.h>
#include <cstdint>
#include <cstddef>

#define B_  2
#define F_  1024
#define N_  2048
#define H_  16
#define D_  64

typedef __attribute__((ext_vector_type(8))) __bf16 bf16x8;
typedef __attribute__((ext_vector_type(4))) float f32x4;

__device__ __forceinline__ unsigned short f2bf(float f) {
  union { float f; unsigned int u; } v; v.f = f;
  unsigned int r = v.u + 0x7FFFu + ((v.u >> 16) & 1u);
  return (unsigned short)(r >> 16);
}

__device__ __forceinline__ void gload16(const void* g, void* l) {
  __builtin_amdgcn_global_load_lds(
      (__attribute__((address_space(1))) void*)g,
      (__attribute__((address_space(3))) void*)l, 16, 0, 0);
}

// ---------------------------------------------------------------------------
// Transpose + fp32->bf16: x[b][i][n] -> XT[b][n][i]   (grid: N/32, F/32, 3*B)
// ---------------------------------------------------------------------------
__global__ __launch_bounds__(256) void k_transpose_cvt(
    const float* __restrict__ q, const float* __restrict__ k,
    const float* __restrict__ v, unsigned short* __restrict__ out)
{
  __shared__ float t[32][33];
  const int which = blockIdx.z >> 1;
  const int b = blockIdx.z & 1;
  const float* src = (which == 0) ? q : (which == 1) ? k : v;
  src += (size_t)b * (F_ * N_);
  unsigned short* dst = out + (size_t)which * ((size_t)B_ * N_ * F_) + (size_t)b * (N_ * F_);
  const int tid = threadIdx.x;
  const int r = tid >> 3, c4 = (tid & 7) << 2;
  float4 d = *(const float4*)(src + (size_t)(blockIdx.y * 32 + r) * N_ + blockIdx.x * 32 + c4);
  t[r][c4 + 0] = d.x; t[r][c4 + 1] = d.y; t[r][c4 + 2] = d.z; t[r][c4 + 3] = d.w;
  __syncthreads();
  unsigned long long pk =
      (unsigned long long)f2bf(t[c4 + 0][r]) |
      ((unsigned long long)f2bf(t[c4 + 1][r]) << 16) |
      ((unsigned long long)f2bf(t[c4 + 2][r]) << 32) |
      ((unsigned long long)f2bf(t[c4 + 3][r]) << 48);
  *(unsigned long long*)(dst + (size_t)(blockIdx.x * 32 + r) * F_ + blockIdx.y * 32 + c4) = pk;
}

// ---------------------------------------------------------------------------
// Weight convert (+ head-major permute). o' = h*64+dd <-> o = dd*16+h.
// z=0: wq rows permuted; z=1: wk rows permuted; z=2: wv plain; z=3: wm cols permuted
// grid: (1024, 4)
// ---------------------------------------------------------------------------
__global__ __launch_bounds__(256) void k_cvt_weights(
    const float* __restrict__ wq, const float* __restrict__ wk,
    const float* __restrict__ wv, const float* __restrict__ wm,
    unsigned short* __restrict__ W2q, unsigned short* __restrict__ W2k,
    unsigned short* __restrict__ Wv2, unsigned short* __restrict__ Wm2)
{
  const int z = blockIdx.y;
  const int idx = (blockIdx.x * 256 + threadIdx.x) * 4;
  const int orow = idx >> 10;
  const int cb = idx & 1023;
  float a, b2, c, d2;
  unsigned short* dst;
  if (z <= 1) {
    const float* w = z ? wk : wq;
    const int o = ((orow & 63) << 4) | (orow >> 6);
    float4 d4 = *(const float4*)(w + (size_t)o * 1024 + cb);
    a = d4.x; b2 = d4.y; c = d4.z; d2 = d4.w;
    dst = z ? W2k : W2q;
  } else if (z == 2) {
    float4 d4 = *(const float4*)(wv + idx);
    a = d4.x; b2 = d4.y; c = d4.z; d2 = d4.w;
    dst = Wv2;
  } else {
    const float* wrow = wm + (size_t)orow * 1024;
    int f0 = cb;
    a  = wrow[((f0 & 63) << 4) | (f0 >> 6)]; f0++;
    b2 = wrow[((f0 & 63) << 4) | (f0 >> 6)]; f0++;
    c  = wrow[((f0 & 63) << 4) | (f0 >> 6)]; f0++;
    d2 = wrow[((f0 & 63) << 4) | (f0 >> 6)];
    dst = Wm2;
  }
  unsigned long long pk = (unsigned long long)f2bf(a) |
      ((unsigned long long)f2bf(b2) << 16) |
      ((unsigned long long)f2bf(c) << 32) |
      ((unsigned long long)f2bf(d2) << 48);
  *(unsigned long long*)(dst + idx) = pk;
}

// ---------------------------------------------------------------------------
// gemm_bt: D[row,col] = sum_k A[row,k]*Bt[col,k]  (K=1024, lda=ldb=1024 elems)
// 128x128 tile, 4 waves (2x2 of 64x64), BK=64, mfma 16x16x32 bf16.
// mode 0 (QK proj): A batched (XT), out = Qt/Kt [b][h][n][dd] bf16,
//                   bias idx = orig o of col, out = (acc+bias)*scale
// mode 1 (V proj):  Bt batched, out = Yv[b][f][m] bf16, bias[row]
// mode 2 (merge):   Bt batched, out = fp32 d_out [b][o][n], bias[row]
// ---------------------------------------------------------------------------
__global__ __launch_bounds__(256) void k_gemm_bt(
    const unsigned short* __restrict__ A, const unsigned short* __restrict__ Bt,
    const float* __restrict__ bias, void* __restrict__ Cout,
    int mode, float scale)
{
  __shared__ __align__(16) char sA[16384];
  __shared__ __align__(16) char sB[16384];
  const int tid = threadIdx.x;
  const int l = tid & 63, w = tid >> 6;
  const int lr = l & 15, lg = l >> 4;
  const int bx = blockIdx.x, by = blockIdx.y, zb = blockIdx.z;
  const char* Ab = (const char*)A;
  const char* Bb = (const char*)Bt;
  if (mode == 0) Ab += (size_t)zb * ((size_t)N_ * F_ * 2);
  else           Bb += (size_t)zb * ((size_t)N_ * F_ * 2);
  const int wr = w >> 1, wc = w & 1;

  f32x4 acc[4][4];
  const f32x4 zero = {0.f, 0.f, 0.f, 0.f};
#pragma unroll
  for (int i = 0; i < 4; ++i)
#pragma unroll
    for (int j = 0; j < 4; ++j) acc[i][j] = zero;

  for (int kt = 0; kt < 16; ++kt) {
#pragma unroll
    for (int c = 0; c < 4; ++c) {
      const int D = c * 4096 + w * 1024 + l * 16;
      const int row = D >> 7, inner = D & 127;
      const int swz = inner ^ ((row & 7) << 4);
      gload16(Ab + ((size_t)(bx * 128 + row) * 1024 + kt * 64) * 2 + swz,
              sA + c * 4096 + w * 1024);
      gload16(Bb + ((size_t)(by * 128 + row) * 1024 + kt * 64) * 2 + swz,
              sB + c * 4096 + w * 1024);
    }
    __syncthreads();
#pragma unroll
    for (int kk = 0; kk < 2; ++kk) {
      bf16x8 af[4], bfv[4];
#pragma unroll
      for (int i = 0; i < 4; ++i) {
        const int row = wr * 64 + i * 16 + lr;
        af[i] = *(const bf16x8*)(sA + row * 128 + ((kk * 64 + lg * 16) ^ ((row & 7) << 4)));
      }
#pragma unroll
      for (int j = 0; j < 4; ++j) {
        const int row = wc * 64 + j * 16 + lr;
        bfv[j] = *(const bf16x8*)(sB + row * 128 + ((kk * 64 + lg * 16) ^ ((row & 7) << 4)));
      }
#pragma unroll
      for (int i = 0; i < 4; ++i)
#pragma unroll
        for (int j = 0; j < 4; ++j)
          acc[i][j] = __builtin_amdgcn_mfma_f32_16x16x32_bf16(af[i], bfv[j], acc[i][j], 0, 0, 0);
    }
    __syncthreads();
  }

#pragma unroll
  for (int i = 0; i < 4; ++i) {
#pragma unroll
    for (int j = 0; j < 4; ++j) {
      const int row0 = bx * 128 + wr * 64 + i * 16 + lg * 4;
      const int col = by * 128 + wc * 64 + j * 16 + lr;
#pragma unroll
      for (int r = 0; r < 4; ++r) {
        float v = acc[i][j][r];
        const int row = row0 + r;
        if (mode == 0) {
          v = (v + bias[((col & 63) << 4) | (col >> 6)]) * scale;
          ((unsigned short*)Cout)[(size_t)zb * 2097152 + (size_t)(col >> 6) * 131072 +
                                  (size_t)row * 64 + (col & 63)] = f2bf(v);
        } else if (mode == 1) {
          v += bias[row];
          ((unsigned short*)Cout)[(size_t)zb * 2097152 + (size_t)row * 2048 + col] = f2bf(v);
        } else {
          v += bias[row];
          ((float*)Cout)[(size_t)zb * 2097152 + (size_t)row * 2048 + col] = v;
        }
      }
    }
  }
}

// ---------------------------------------------------------------------------
// Fused attention: per (qblock, h, b). 4 waves x 16 q-rows, MBLK=128.
// Pass 1: online row max/sum.  Pass 2: recompute scores, write prob fp32,
// P->bf16 via LDS, PV MFMA accumulate.  X2t[b][n][h*64+dd] bf16.
// grid: (32, 16, 2)
// ---------------------------------------------------------------------------
__global__ __launch_bounds__(256) void k_attn(
    const unsigned short* __restrict__ Qt, const unsigned short* __restrict__ Kt,
    const unsigned short* __restrict__ Yv, float* __restrict__ prob,
    unsigned short* __restrict__ X2t)
{
  __shared__ __align__(16) char sK[16384];   // [128 m][64 dd] bf16, swizzled
  __shared__ __align__(16) char sV[16384];   // [64 dd][128 m] bf16, swizzled
  __shared__ __align__(16) char sP[16384];   // [64 n][128 m] bf16, swizzled
  const int tid = threadIdx.x;
  const int l = tid & 63, w = tid >> 6;
  const int lr = l & 15, lg = l >> 4;
  const int qb = blockIdx.x, h = blockIdx.y, b = blockIdx.z;
  const int n0 = qb * 64 + w * 16;

  const char* Qh = (const char*)(Qt + (size_t)(b * 16 + h) * (2048 * 64));
  const char* Kh = (const char*)(Kt + (size_t)(b * 16 + h) * (2048 * 64));
  const char* Vh = (const char*)(Yv + (size_t)b * (1024 * 2048) + (size_t)h * 2048);
  float* probh = prob + (size_t)(b * 16 + h) * ((size_t)2048 * 2048);

  // Q fragments (scale 1/8 already folded into Qt)
  bf16x8 qf0 = *(const bf16x8*)(Qh + (size_t)(n0 + lr) * 128 + lg * 16);
  bf16x8 qf1 = *(const bf16x8*)(Qh + (size_t)(n0 + lr) * 128 + 64 + lg * 16);

  auto stage_k = [&](int mt) {
#pragma unroll
    for (int c = 0; c < 4; ++c) {
      const int D = c * 4096 + w * 1024 + l * 16;
      const int row = D >> 7, inner = D & 127;
      gload16(Kh + (size_t)(mt * 128 + row) * 128 + (inner ^ ((row & 7) << 4)),
              sK + c * 4096 + w * 1024);
    }
  };
  auto stage_v = [&](int mt) {
#pragma unroll
    for (int c = 0; c < 4; ++c) {
      const int D = c * 4096 + w * 1024 + l * 16;
      const int row = D >> 8, inner = D & 255;
      gload16(Vh + (size_t)row * 65536 + (size_t)mt * 256 + (inner ^ ((row & 15) << 4)),
              sV + c * 4096 + w * 1024);
    }
  };

  float mrun[4], lrun[4];
#pragma unroll
  for (int r = 0; r < 4; ++r) { mrun[r] = -1e30f; lrun[r] = 0.f; }

  // ---------------- pass 1: online max & sum ----------------
  for (int mt = 0; mt < 16; ++mt) {
    stage_k(mt);
    __syncthreads();
    f32x4 s[8];
    const f32x4 zero = {0.f, 0.f, 0.f, 0.f};
#pragma unroll
    for (int j = 0; j < 8; ++j) s[j] = zero;
#pragma unroll
    for (int kk = 0; kk < 2; ++kk) {
      bf16x8 qf = kk ? qf1 : qf0;
#pragma unroll
      for (int j = 0; j < 8; ++j) {
        const int row = j * 16 + lr;
        bf16x8 kf = *(const bf16x8*)(sK + row * 128 + ((kk * 64 + lg * 16) ^ ((row & 7) << 4)));
        s[j] = __builtin_amdgcn_mfma_f32_16x16x32_bf16(qf, kf, s[j], 0, 0, 0);
      }
    }
    __syncthreads();
#pragma unroll
    for (int r = 0; r < 4; ++r) {
      float m_ = s[0][r];
#pragma unroll
      for (int j = 1; j < 8; ++j) m_ = fmaxf(m_, s[j][r]);
#pragma unroll
      for (int d_ = 1; d_ < 16; d_ <<= 1) m_ = fmaxf(m_, __shfl_xor(m_, d_));
      const float mn = fmaxf(mrun[r], m_);
      float ps = 0.f;
#pragma unroll
      for (int j = 0; j < 8; ++j) ps += __expf(s[j][r] - mn);
#pragma unroll
      for (int d_ = 1; d_ < 16; d_ <<= 1) ps += __shfl_xor(ps, d_);
      lrun[r] = lrun[r] * __expf(mrun[r] - mn) + ps;
      mrun[r] = mn;
    }
  }

  float linv[4];
#pragma unroll
  for (int r = 0; r < 4; ++r) linv[r] = 1.f / lrun[r];

  f32x4 acc[4];
  {
    const f32x4 zero = {0.f, 0.f, 0.f, 0.f};
#pragma unroll
    for (int t = 0; t < 4; ++t) acc[t] = zero;
  }

  // ---------------- pass 2: emit prob + PV ----------------
  for (int mt = 0; mt < 16; ++mt) {
    stage_k(mt);
    stage_v(mt);
    __syncthreads();
    f32x4 s[8];
    const f32x4 zero = {0.f, 0.f, 0.f, 0.f};
#pragma unroll
    for (int j = 0; j < 8; ++j) s[j] = zero;
#pragma unroll
    for (int kk = 0; kk < 2; ++kk) {
      bf16x8 qf = kk ? qf1 : qf0;
#pragma unroll
      for (int j = 0; j < 8; ++j) {
        const int row = j * 16 + lr;
        bf16x8 kf = *(const bf16x8*)(sK + row * 128 + ((kk * 64 + lg * 16) ^ ((row & 7) << 4)));
        s[j] = __builtin_amdgcn_mfma_f32_16x16x32_bf16(qf, kf, s[j], 0, 0, 0);
      }
    }
#pragma unroll
    for (int j = 0; j < 8; ++j) {
#pragma unroll
      for (int r = 0; r < 4; ++r) {
        const float e = __expf(s[j][r] - mrun[r]) * linv[r];
        const int n_ = n0 + lg * 4 + r;
        probh[(size_t)n_ * 2048 + mt * 128 + j * 16 + lr] = e;
        const int nloc = w * 16 + lg * 4 + r;
        *(unsigned short*)(sP + nloc * 256 + (((j * 16 + lr) * 2) ^ ((nloc & 15) << 4))) = f2bf(e);
      }
    }
    // PV: acc[t] over dd = t*16+lr, rows n = wave band
#pragma unroll
    for (int ks = 0; ks < 4; ++ks) {
      const int nr = w * 16 + lr;
      bf16x8 pa = *(const bf16x8*)(sP + nr * 256 + ((ks * 64 + lg * 16) ^ ((nr & 15) << 4)));
#pragma unroll
      for (int t = 0; t < 4; ++t) {
        const int vr = t * 16 + lr;
        bf16x8 vf = *(const bf16x8*)(sV + vr * 256 + ((ks * 64 + lg * 16) ^ ((vr & 15) << 4)));
        acc[t] = __builtin_amdgcn_mfma_f32_16x16x32_bf16(pa, vf, acc[t], 0, 0, 0);
      }
    }
    __syncthreads();
  }

  // epilogue: X2t[b][n][h*64 + dd]
#pragma unroll
  for (int t = 0; t < 4; ++t) {
#pragma unroll
    for (int r = 0; r < 4; ++r) {
      const int n_ = n0 + lg * 4 + r;
      X2t[((size_t)b * 2048 + n_) * 1024 + h * 64 + t * 16 + lr] = f2bf(acc[t][r]);
    }
  }
}

// ---------------------------------------------------------------------------
extern "C" void kernel_launch(void* const* d_in, const int* in_sizes, int n_in,
                              void* d_out, int out_size, void* d_ws, size_t ws_size,
                              hipStream_t stream)
{
  const float* query = (const float*)d_in[0];
  const float* key_  = (const float*)d_in[1];
  const float* value = (const float*)d_in[2];
  const float* wq = (const float*)d_in[3];
  const float* bq = (const float*)d_in[4];
  const float* wk = (const float*)d_in[5];
  const float* bk = (const float*)d_in[6];
  const float* wv = (const float*)d_in[7];
  const float* bv = (const float*)d_in[8];
  const float* wm = (const float*)d_in[9];
  const float* bm = (const float*)d_in[10];

  char* ws = (char*)d_ws;
  unsigned short* XT  = (unsigned short*)(ws);             // 3 x [B][N][F] bf16
  unsigned short* W2q = (unsigned short*)(ws + 25165824);
  unsigned short* W2k = (unsigned short*)(ws + 27262976);
  unsigned short* Wv2 = (unsigned short*)(ws + 29360128);
  unsigned short* Wm2 = (unsigned short*)(ws + 31457280);
  unsigned short* Qt  = (unsigned short*)(ws + 33554432);  // [B][H][N][64] bf16
  unsigned short* Kt  = (unsigned short*)(ws + 41943040);  // [B][H][N][64] bf16
  unsigned short* Yv  = (unsigned short*)(ws + 50331648);  // [B][F][N] bf16
  unsigned short* X2t = (unsigned short*)(ws + 58720256);  // [B][N][F'] bf16

  unsigned short* XTq = XT;
  unsigned short* XTk = XT + 4194304;
  unsigned short* XTv = XT + 8388608;

  float* outp = (float*)d_out;
  float* prob = outp + 4194304;

  k_transpose_cvt<<<dim3(64, 32, 6), 256, 0, stream>>>(query, key_, value, XT);
  k_cvt_weights<<<dim3(1024, 4, 1), 256, 0, stream>>>(wq, wk, wv, wm, W2q, W2k, Wv2, Wm2);
  // Q: scale 1/8 folded; K: scale 1
  k_gemm_bt<<<dim3(16, 8, 2), 256, 0, stream>>>(XTq, W2q, bq, (void*)Qt, 0, 0.125f);
  k_gemm_bt<<<dim3(16, 8, 2), 256, 0, stream>>>(XTk, W2k, bk, (void*)Kt, 0, 1.0f);
  k_gemm_bt<<<dim3(8, 16, 2), 256, 0, stream>>>(Wv2, XTv, bv, (void*)Yv, 1, 1.0f);
  k_attn<<<dim3(32, 16, 2), 256, 0, stream>>>(Qt, Kt, Yv, prob, X2t);
  k_gemm_bt<<<dim3(8, 16, 2), 256, 0, stream>>>(Wm2, X2t, bm, (void*)outp, 2, 1.0f);
}

// Round 7
// 789.235 us; speedup vs baseline: 1.0744x; 1.0744x over previous
//
#include <hip/hip_runtime.h>
#include <cstdint>
#include <cstddef>

#define B_  2
#define F_  1024
#define N_  2048
#define H_  16

typedef __attribute__((ext_vector_type(8))) __bf16 bf16x8;
typedef __attribute__((ext_vector_type(4))) __bf16 bf16x4;
typedef __attribute__((ext_vector_type(4))) float f32x4;

#define WAITV(n) asm volatile("s_waitcnt vmcnt(" n ")" ::: "memory")
#define BAR() do { asm volatile("" ::: "memory"); __builtin_amdgcn_s_barrier(); asm volatile("" ::: "memory"); } while (0)

__device__ __forceinline__ unsigned short f2bf(float f) {
  union { float f; unsigned int u; } v; v.f = f;
  unsigned int r = v.u + 0x7FFFu + ((v.u >> 16) & 1u);
  return (unsigned short)(r >> 16);
}

__device__ __forceinline__ void gload16(const void* g, void* l) {
  __builtin_amdgcn_global_load_lds(
      (__attribute__((address_space(1))) void*)g,
      (__attribute__((address_space(3))) void*)l, 16, 0, 0);
}

__device__ __forceinline__ f32x4 vmax4(f32x4 x, f32x4 y) {
  f32x4 r; r[0]=fmaxf(x[0],y[0]); r[1]=fmaxf(x[1],y[1]); r[2]=fmaxf(x[2],y[2]); r[3]=fmaxf(x[3],y[3]); return r;
}

// ---------------------------------------------------------------------------
// Transpose + fp32->bf16: x[b][i][n] -> XT[b][n][i]   (grid: N/32, F/32, 3*B)
// ---------------------------------------------------------------------------
__global__ __launch_bounds__(256) void k_transpose_cvt(
    const float* __restrict__ q, const float* __restrict__ k,
    const float* __restrict__ v, unsigned short* __restrict__ out)
{
  __shared__ float t[32][33];
  const int which = blockIdx.z >> 1;
  const int b = blockIdx.z & 1;
  const float* src = (which == 0) ? q : (which == 1) ? k : v;
  src += (size_t)b * (F_ * N_);
  unsigned short* dst = out + (size_t)which * ((size_t)B_ * N_ * F_) + (size_t)b * (N_ * F_);
  const int tid = threadIdx.x;
  const int r = tid >> 3, c4 = (tid & 7) << 2;
  float4 d = *(const float4*)(src + (size_t)(blockIdx.y * 32 + r) * N_ + blockIdx.x * 32 + c4);
  t[r][c4 + 0] = d.x; t[r][c4 + 1] = d.y; t[r][c4 + 2] = d.z; t[r][c4 + 3] = d.w;
  __syncthreads();
  unsigned long long pk =
      (unsigned long long)f2bf(t[c4 + 0][r]) |
      ((unsigned long long)f2bf(t[c4 + 1][r]) << 16) |
      ((unsigned long long)f2bf(t[c4 + 2][r]) << 32) |
      ((unsigned long long)f2bf(t[c4 + 3][r]) << 48);
  *(unsigned long long*)(dst + (size_t)(blockIdx.x * 32 + r) * F_ + blockIdx.y * 32 + c4) = pk;
}

// ---------------------------------------------------------------------------
// Weight convert (+ head-major permute). o' = h*64+dd <-> o = dd*16+h.
// z=0: wq rows permuted; z=1: wk rows permuted; z=2: wv plain; z=3: wm cols permuted
// ---------------------------------------------------------------------------
__global__ __launch_bounds__(256) void k_cvt_weights(
    const float* __restrict__ wq, const float* __restrict__ wk,
    const float* __restrict__ wv, const float* __restrict__ wm,
    unsigned short* __restrict__ W2q, unsigned short* __restrict__ W2k,
    unsigned short* __restrict__ Wv2, unsigned short* __restrict__ Wm2)
{
  const int z = blockIdx.y;
  const int idx = (blockIdx.x * 256 + threadIdx.x) * 4;
  const int orow = idx >> 10;
  const int cb = idx & 1023;
  float a, b2, c, d2;
  unsigned short* dst;
  if (z <= 1) {
    const float* w = z ? wk : wq;
    const int o = ((orow & 63) << 4) | (orow >> 6);
    float4 d4 = *(const float4*)(w + (size_t)o * 1024 + cb);
    a = d4.x; b2 = d4.y; c = d4.z; d2 = d4.w;
    dst = z ? W2k : W2q;
  } else if (z == 2) {
    float4 d4 = *(const float4*)(wv + idx);
    a = d4.x; b2 = d4.y; c = d4.z; d2 = d4.w;
    dst = Wv2;
  } else {
    const float* wrow = wm + (size_t)orow * 1024;
    int f0 = cb;
    a  = wrow[((f0 & 63) << 4) | (f0 >> 6)]; f0++;
    b2 = wrow[((f0 & 63) << 4) | (f0 >> 6)]; f0++;
    c  = wrow[((f0 & 63) << 4) | (f0 >> 6)]; f0++;
    d2 = wrow[((f0 & 63) << 4) | (f0 >> 6)];
    dst = Wm2;
  }
  unsigned long long pk = (unsigned long long)f2bf(a) |
      ((unsigned long long)f2bf(b2) << 16) |
      ((unsigned long long)f2bf(c) << 32) |
      ((unsigned long long)f2bf(d2) << 48);
  *(unsigned long long*)(dst + idx) = pk;
}

// ---------------------------------------------------------------------------
// gemm64: D[row,col] = sum_k A[row,k]*Bt[col,k]  (K=1024), 64x64 tile,
// 4 waves (2x2 of 32x32), BK=64, double-buffered LDS, counted vmcnt prefetch.
// mode 0 (Q/K proj): A batched (XT), out Qt/Kt [b][h][n][dd] bf16, bias by orig col, *scale
// mode 1 (V proj):   Bt batched, out Yv[b][f][m] bf16, bias[row]
// mode 2 (merge):    Bt batched, out fp32 d_out [b][o][n], bias[row]
// ---------------------------------------------------------------------------
__global__ __launch_bounds__(256) void k_gemm64(
    const unsigned short* __restrict__ A, const unsigned short* __restrict__ Bt,
    const float* __restrict__ bias, void* __restrict__ Cout,
    int mode, float scale)
{
  __shared__ __align__(16) char sA[2][8192];
  __shared__ __align__(16) char sB[2][8192];
  const int tid = threadIdx.x;
  const int l = tid & 63, w = tid >> 6;
  const int lr = l & 15, lg = l >> 4;
  const int bx = blockIdx.x, by = blockIdx.y, zb = blockIdx.z;
  const char* Ab = (const char*)A;
  const char* Bb = (const char*)Bt;
  if (mode == 0) Ab += (size_t)zb * ((size_t)N_ * F_ * 2);
  else           Bb += (size_t)zb * ((size_t)N_ * F_ * 2);
  const int wr = w >> 1, wc = w & 1;

  f32x4 acc[2][2];
  const f32x4 zero = {0.f, 0.f, 0.f, 0.f};
#pragma unroll
  for (int i = 0; i < 2; ++i)
#pragma unroll
    for (int j = 0; j < 2; ++j) acc[i][j] = zero;

  auto stage = [&](int kt, int bf) {
#pragma unroll
    for (int c = 0; c < 2; ++c) {
      const int D = c * 4096 + tid * 16;
      const int row = D >> 7, inner = D & 127;
      const int swz = inner ^ ((row & 7) << 4);
      gload16(Ab + ((size_t)(bx * 64 + row) * 1024 + kt * 64) * 2 + swz,
              &sA[bf][c * 4096 + w * 1024]);
      gload16(Bb + ((size_t)(by * 64 + row) * 1024 + kt * 64) * 2 + swz,
              &sB[bf][c * 4096 + w * 1024]);
    }
  };

  stage(0, 0);
  int buf = 0;
  for (int kt = 0; kt < 16; ++kt) {
    if (kt < 15) { stage(kt + 1, buf ^ 1); WAITV("4"); }
    else         { WAITV("0"); }
    BAR();
#pragma unroll
    for (int kk = 0; kk < 2; ++kk) {
      bf16x8 af[2], bfv[2];
#pragma unroll
      for (int i = 0; i < 2; ++i) {
        const int row = wr * 32 + i * 16 + lr;
        af[i] = *(const bf16x8*)(&sA[buf][row * 128 + ((kk * 64 + lg * 16) ^ ((row & 7) << 4))]);
      }
#pragma unroll
      for (int j = 0; j < 2; ++j) {
        const int row = wc * 32 + j * 16 + lr;
        bfv[j] = *(const bf16x8*)(&sB[buf][row * 128 + ((kk * 64 + lg * 16) ^ ((row & 7) << 4))]);
      }
#pragma unroll
      for (int i = 0; i < 2; ++i)
#pragma unroll
        for (int j = 0; j < 2; ++j)
          acc[i][j] = __builtin_amdgcn_mfma_f32_16x16x32_bf16(af[i], bfv[j], acc[i][j], 0, 0, 0);
    }
    BAR();
    buf ^= 1;
  }

#pragma unroll
  for (int i = 0; i < 2; ++i) {
#pragma unroll
    for (int j = 0; j < 2; ++j) {
      const int row0 = bx * 64 + wr * 32 + i * 16 + lg * 4;
      const int col = by * 64 + wc * 32 + j * 16 + lr;
#pragma unroll
      for (int r = 0; r < 4; ++r) {
        float v = acc[i][j][r];
        const int row = row0 + r;
        if (mode == 0) {
          v = (v + bias[((col & 63) << 4) | (col >> 6)]) * scale;
          ((unsigned short*)Cout)[(size_t)zb * 2097152 + (size_t)(col >> 6) * 131072 +
                                  (size_t)row * 64 + (col & 63)] = f2bf(v);
        } else if (mode == 1) {
          v += bias[row];
          ((unsigned short*)Cout)[(size_t)zb * 2097152 + (size_t)row * 2048 + col] = f2bf(v);
        } else {
          v += bias[row];
          ((float*)Cout)[(size_t)zb * 2097152 + (size_t)row * 2048 + col] = v;
        }
      }
    }
  }
}

// ---------------------------------------------------------------------------
// Fused attention, swapped-QK layout. grid (32,16,2), 4 waves x 16 q-rows.
// Each lane owns ONE q-row (n = qb*64 + w*16 + (l&15)); regs hold m-slices.
// Pass 1: online row max/sum (2 shuffles). Pass 2: recompute scores, write
// prob as float4 direct from regs, P->bf16 via per-wave swizzled LDS (b64
// writes / b128 reads), PV MFMA. Double-buffered K/V staging, counted vmcnt.
// ---------------------------------------------------------------------------
__global__ __launch_bounds__(256) void k_attn(
    const unsigned short* __restrict__ Qt, const unsigned short* __restrict__ Kt,
    const unsigned short* __restrict__ Yv, float* __restrict__ prob,
    unsigned short* __restrict__ X2t)
{
  __shared__ __align__(16) char sK[2][16384];   // [128 m][64 dd] bf16, swz (row&7)<<4
  __shared__ __align__(16) char sV[2][16384];   // [64 dd][128 m] bf16, swz (row&15)<<4
  __shared__ __align__(16) char sP[16384];      // per-wave [16 n][128 m] bf16, 8B-granule XOR swz
  const int tid = threadIdx.x;
  const int l = tid & 63, w = tid >> 6;
  const int lr = l & 15, lg = l >> 4;
  const int qb = blockIdx.x, h = blockIdx.y, b = blockIdx.z;
  const int nl = qb * 64 + w * 16 + lr;         // this lane's q row

  const char* Qh = (const char*)(Qt + (size_t)(b * 16 + h) * (2048 * 64));
  const char* Kh = (const char*)(Kt + (size_t)(b * 16 + h) * (2048 * 64));
  const char* Vh = (const char*)(Yv + (size_t)b * (1024 * 2048) + (size_t)h * 2048);
  float* probh = prob + (size_t)(b * 16 + h) * ((size_t)2048 * 2048) + (size_t)nl * 2048;

  // Q fragments (scale 1/8 folded into Qt): Q[nl][kk*32 + lg*8 .. +7]
  bf16x8 qf0 = *(const bf16x8*)(Qh + (size_t)nl * 128 + lg * 16);
  bf16x8 qf1 = *(const bf16x8*)(Qh + (size_t)nl * 128 + 64 + lg * 16);

  auto stage_k = [&](int mt, int bf) {
#pragma unroll
    for (int c = 0; c < 4; ++c) {
      const int D = c * 4096 + w * 1024 + l * 16;
      const int row = D >> 7, inner = D & 127;
      gload16(Kh + (size_t)(mt * 128 + row) * 128 + (inner ^ ((row & 7) << 4)),
              &sK[bf][c * 4096 + w * 1024]);
    }
  };
  auto stage_v = [&](int mt, int bf) {
#pragma unroll
    for (int c = 0; c < 4; ++c) {
      const int D = c * 4096 + w * 1024 + l * 16;
      const int row = D >> 8, inner = D & 255;
      gload16(Vh + (size_t)row * 65536 + (size_t)mt * 256 + (inner ^ ((row & 15) << 4)),
              &sV[bf][c * 4096 + w * 1024]);
    }
  };

  float mrun = -1e30f, lrun = 0.f;

  // ---------------- pass 1: online max & sum ----------------
  stage_k(0, 0);
  int buf = 0;
  for (int mt = 0; mt < 16; ++mt) {
    if (mt < 15) { stage_k(mt + 1, buf ^ 1); WAITV("4"); }
    else         { WAITV("0"); }
    BAR();
    f32x4 s[8];
    const f32x4 zero = {0.f, 0.f, 0.f, 0.f};
#pragma unroll
    for (int j = 0; j < 8; ++j) s[j] = zero;
#pragma unroll
    for (int kk = 0; kk < 2; ++kk) {
      bf16x8 qf = kk ? qf1 : qf0;
#pragma unroll
      for (int j = 0; j < 8; ++j) {
        const int row = j * 16 + lr;
        bf16x8 kf = *(const bf16x8*)(&sK[buf][row * 128 + ((kk * 64 + lg * 16) ^ ((row & 7) << 4))]);
        s[j] = __builtin_amdgcn_mfma_f32_16x16x32_bf16(kf, qf, s[j], 0, 0, 0);
      }
    }
    BAR();                                   // all sK reads done; overlap softmax w/ next stage
    f32x4 a0 = vmax4(s[0], s[1]), a1 = vmax4(s[2], s[3]);
    f32x4 a2 = vmax4(s[4], s[5]), a3 = vmax4(s[6], s[7]);
    a0 = vmax4(a0, a1); a2 = vmax4(a2, a3); a0 = vmax4(a0, a2);
    float mx = fmaxf(fmaxf(a0[0], a0[1]), fmaxf(a0[2], a0[3]));
    mx = fmaxf(mx, __shfl_xor(mx, 16));
    mx = fmaxf(mx, __shfl_xor(mx, 32));
    const float mn = fmaxf(mrun, mx);
    f32x4 ps4 = zero;
#pragma unroll
    for (int j = 0; j < 8; ++j) {
      f32x4 e;
#pragma unroll
      for (int r = 0; r < 4; ++r) e[r] = __expf(s[j][r] - mn);
      ps4 += e;
    }
    float ps = (ps4[0] + ps4[1]) + (ps4[2] + ps4[3]);
    ps += __shfl_xor(ps, 16);
    ps += __shfl_xor(ps, 32);
    lrun = lrun * __expf(mrun - mn) + ps;
    mrun = mn;
    buf ^= 1;
  }

  const float linv = 1.f / lrun;

  f32x4 acc[4];
  {
    const f32x4 zero = {0.f, 0.f, 0.f, 0.f};
#pragma unroll
    for (int t = 0; t < 4; ++t) acc[t] = zero;
  }

  // ---------------- pass 2: emit prob (float4) + PV ----------------
  stage_k(0, 0); stage_v(0, 0);
  buf = 0;
  for (int mt = 0; mt < 16; ++mt) {
    if (mt < 15) { stage_k(mt + 1, buf ^ 1); stage_v(mt + 1, buf ^ 1); }
    WAITV("8");                              // drains current tile's loads; prev stores newest
    BAR();
    f32x4 s[8];
    const f32x4 zero = {0.f, 0.f, 0.f, 0.f};
#pragma unroll
    for (int j = 0; j < 8; ++j) s[j] = zero;
#pragma unroll
    for (int kk = 0; kk < 2; ++kk) {
      bf16x8 qf = kk ? qf1 : qf0;
#pragma unroll
      for (int j = 0; j < 8; ++j) {
        const int row = j * 16 + lr;
        bf16x8 kf = *(const bf16x8*)(&sK[buf][row * 128 + ((kk * 64 + lg * 16) ^ ((row & 7) << 4))]);
        s[j] = __builtin_amdgcn_mfma_f32_16x16x32_bf16(kf, qf, s[j], 0, 0, 0);
      }
    }
    // normalized probs: float4 direct store + bf16x4 -> per-wave swizzled sP
#pragma unroll
    for (int j = 0; j < 8; ++j) {
      f32x4 e;
#pragma unroll
      for (int r = 0; r < 4; ++r) e[r] = __expf(s[j][r] - mrun) * linv;
      float4 st; st.x = e[0]; st.y = e[1]; st.z = e[2]; st.w = e[3];
      *(float4*)(probh + mt * 128 + j * 16 + lg * 4) = st;
      bf16x4 pk;
      pk[0] = (__bf16)e[0]; pk[1] = (__bf16)e[1]; pk[2] = (__bf16)e[2]; pk[3] = (__bf16)e[3];
      const int gs = (j * 4 + lg) ^ ((lr & 7) << 1);
      *(bf16x4*)(&sP[w * 4096 + lr * 256 + gs * 8]) = pk;
    }
    // PV: acc[t] -> out[n = band+lg*4+r][dd = t*16+lr]
#pragma unroll
    for (int ks = 0; ks < 4; ++ks) {
      const int g0 = (ks * 8 + lg * 2) ^ ((lr & 7) << 1);
      bf16x8 pa = *(const bf16x8*)(&sP[w * 4096 + lr * 256 + g0 * 8]);
#pragma unroll
      for (int t = 0; t < 4; ++t) {
        const int vr = t * 16 + lr;
        bf16x8 vf = *(const bf16x8*)(&sV[buf][vr * 256 + ((ks * 64 + lg * 16) ^ ((vr & 15) << 4))]);
        acc[t] = __builtin_amdgcn_mfma_f32_16x16x32_bf16(pa, vf, acc[t], 0, 0, 0);
      }
    }
    BAR();
    buf ^= 1;
  }

  // epilogue: X2t[b][n][h*64 + dd]
#pragma unroll
  for (int t = 0; t < 4; ++t) {
#pragma unroll
    for (int r = 0; r < 4; ++r) {
      const int n_ = qb * 64 + w * 16 + lg * 4 + r;
      X2t[((size_t)b * 2048 + n_) * 1024 + h * 64 + t * 16 + lr] = f2bf(acc[t][r]);
    }
  }
}

// ---------------------------------------------------------------------------
extern "C" void kernel_launch(void* const* d_in, const int* in_sizes, int n_in,
                              void* d_out, int out_size, void* d_ws, size_t ws_size,
                              hipStream_t stream)
{
  const float* query = (const float*)d_in[0];
  const float* key_  = (const float*)d_in[1];
  const float* value = (const float*)d_in[2];
  const float* wq = (const float*)d_in[3];
  const float* bq = (const float*)d_in[4];
  const float* wk = (const float*)d_in[5];
  const float* bk = (const float*)d_in[6];
  const float* wv = (const float*)d_in[7];
  const float* bv = (const float*)d_in[8];
  const float* wm = (const float*)d_in[9];
  const float* bm = (const float*)d_in[10];

  char* ws = (char*)d_ws;
  unsigned short* XT  = (unsigned short*)(ws);             // 3 x [B][N][F] bf16
  unsigned short* W2q = (unsigned short*)(ws + 25165824);
  unsigned short* W2k = (unsigned short*)(ws + 27262976);
  unsigned short* Wv2 = (unsigned short*)(ws + 29360128);
  unsigned short* Wm2 = (unsigned short*)(ws + 31457280);
  unsigned short* Qt  = (unsigned short*)(ws + 33554432);  // [B][H][N][64] bf16
  unsigned short* Kt  = (unsigned short*)(ws + 41943040);  // [B][H][N][64] bf16
  unsigned short* Yv  = (unsigned short*)(ws + 50331648);  // [B][F][N] bf16 (f = dd*16+h order)
  unsigned short* X2t = (unsigned short*)(ws + 58720256);  // [B][N][F'] bf16 (head-major)

  unsigned short* XTq = XT;
  unsigned short* XTk = XT + 4194304;
  unsigned short* XTv = XT + 8388608;

  float* outp = (float*)d_out;
  float* prob = outp + 4194304;

  k_transpose_cvt<<<dim3(64, 32, 6), 256, 0, stream>>>(query, key_, value, XT);
  k_cvt_weights<<<dim3(1024, 4, 1), 256, 0, stream>>>(wq, wk, wv, wm, W2q, W2k, Wv2, Wm2);
  k_gemm64<<<dim3(32, 16, 2), 256, 0, stream>>>(XTq, W2q, bq, (void*)Qt, 0, 0.125f);
  k_gemm64<<<dim3(32, 16, 2), 256, 0, stream>>>(XTk, W2k, bk, (void*)Kt, 0, 1.0f);
  k_gemm64<<<dim3(16, 32, 2), 256, 0, stream>>>(Wv2, XTv, bv, (void*)Yv, 1, 1.0f);
  k_attn<<<dim3(32, 16, 2), 256, 0, stream>>>(Qt, Kt, Yv, prob, X2t);
  k_gemm64<<<dim3(16, 32, 2), 256, 0, stream>>>(Wm2, X2t, bm, (void*)outp, 2, 1.0f);
}